// Round 9
// baseline (615.795 us; speedup 1.0000x reference)
//
#include <hip/hip_runtime.h>
#include <hip/hip_bf16.h>
#include <math.h>

// ---------------------------------------------------------------------------
// GCN anomaly detector.
// Round 8 fix: agg FETCH invariant at 167MB across 3 rewrites -> L2-miss-
// traffic bound (per-XCD compulsory ~12.5MB x8 = 100MB floor; random order
// thrashes to 167MB). Now: (a) bucketbuild does an in-LDS counting sort by
// src-bin so per-dst CSR lists are ~src-ascending; (b) agg kernels become
// windowed walkers: all slots co-resident, each advances its sorted lists
// only to the current src-window boundary -> whole chip sweeps the feature
// table coherently, active window (0.5-2MB) stays L2-resident. Window logic
// and sortedness are performance heuristics only: every edge is processed
// exactly once in any order, so overflow/unsorted fallbacks stay correct.
// ---------------------------------------------------------------------------

__global__ void k_detect(const unsigned int* __restrict__ w, int npairs,
                         int* __restrict__ meta) {
  __shared__ int any;
  if (threadIdx.x == 0) any = 0;
  __syncthreads();
  int local = 0;
  for (int i = threadIdx.x; i < npairs; i += blockDim.x)
    local |= (w[2 * i + 1] != 0u);
  if (local) atomicOr(&any, 1);
  __syncthreads();
  if (threadIdx.x == 0) meta[0] = any ? 0 : 1;  // 1 => edge_index is int64
}

// P1: per-chunk LDS histogram over dst buckets. hist layout: [bin][chunk].
__global__ __launch_bounds__(256) void k_binhist(const void* __restrict__ ei,
                                                 int E, int CS, int B, int shift,
                                                 const int* __restrict__ meta,
                                                 int* __restrict__ hist, int C) {
  __shared__ int lh[256];
  int c = blockIdx.x;
  for (int i = threadIdx.x; i < B; i += 256) lh[i] = 0;
  __syncthreads();
  int e0 = c * CS, e1 = min(E, e0 + CS);
  bool is64 = meta[0] != 0;
  for (int e = e0 + threadIdx.x; e < e1; e += 256) {
    int d = is64 ? (int)((const long long*)ei)[(long)E + e]
                 : ((const int*)ei)[(long)E + e];
    atomicAdd(&lh[d >> shift], 1);
  }
  __syncthreads();
  for (int b = threadIdx.x; b < B; b += 256) hist[(long)b * C + c] = lh[b];
}

// P3: re-read edges, write packed (dstInBucket<<SB | src) into reserved
// per-(chunk,bin) ranges. LDS cursors only -> zero global atomics.
__global__ __launch_bounds__(256) void k_binscatter(const void* __restrict__ ei,
                                                    int E, int CS, int B, int shift,
                                                    int SB,
                                                    const int* __restrict__ meta,
                                                    const int* __restrict__ scan,
                                                    int C, unsigned* __restrict__ pairs) {
  __shared__ int cur[256];
  int c = blockIdx.x;
  for (int b = threadIdx.x; b < B; b += 256) cur[b] = scan[(long)b * C + c];
  __syncthreads();
  int e0 = c * CS, e1 = min(E, e0 + CS);
  bool is64 = meta[0] != 0;
  unsigned spb1 = (1u << shift) - 1u;
  for (int e = e0 + threadIdx.x; e < e1; e += 256) {
    int s, d;
    if (is64) {
      const long long* p = (const long long*)ei;
      s = (int)p[e]; d = (int)p[(long)E + e];
    } else {
      const int* p = (const int*)ei;
      s = p[e]; d = p[(long)E + e];
    }
    int pos = atomicAdd(&cur[d >> shift], 1);
    pairs[pos] = (((unsigned)d & spb1) << SB) | (unsigned)s;
  }
}

// P4 (fused): per-bucket degree hist -> cnt, dis, rs; then in-LDS counting
// sort of the bucket's edges by src-bin (src>>8) so each dst's final CSR
// list comes out ~src-ascending; then scatter into final CSR via LDS
// cursors. Overflow (> CAP edges) falls back to unsorted scatter (still
// correct -- sum order only affects rounding).
#define BB_CAP 16896
__global__ __launch_bounds__(256) void k_bucketbuild(const unsigned* __restrict__ pairs,
                                                     const int* __restrict__ scan,
                                                     int C, int shift, int SB, int N,
                                                     int* __restrict__ cnt,
                                                     float* __restrict__ dis,
                                                     int* __restrict__ rs,
                                                     int* __restrict__ csr) {
  __shared__ unsigned buf[BB_CAP];    // 66 KB
  __shared__ unsigned buf2[BB_CAP];   // 66 KB
  __shared__ int h[1024];
  __shared__ int sm[256];
  __shared__ int sh[512];
  int bin = blockIdx.x;
  int base = bin << shift;
  int nn = min(N - base, 1 << shift);
  int t = threadIdx.x;
  unsigned smask = (1u << SB) - 1u;
  int p0 = scan[(long)bin * C];
  int p1 = scan[(long)(bin + 1) * C];  // sentinel row gives E for last bucket
  int ne = p1 - p0;
  bool srt = (ne <= BB_CAP);

  // stage bucket pairs in LDS (if they fit)
  if (srt)
    for (int i = t; i < ne; i += 256) buf[i] = pairs[p0 + i];
  for (int i = t; i < 1024; i += 256) h[i] = 0;
  __syncthreads();

  // dst histogram
  for (int i = t; i < ne; i += 256)
    atomicAdd(&h[(srt ? buf[i] : pairs[p0 + i]) >> SB], 1);
  __syncthreads();

  // block exclusive scan of degrees -> cursors r0..r3; emit cnt/dis/rs
  int v0 = h[4 * t], v1 = h[4 * t + 1], v2 = h[4 * t + 2], v3 = h[4 * t + 3];
  int s = v0 + v1 + v2 + v3;
  sm[t] = s;
  __syncthreads();
  for (int off = 1; off < 256; off <<= 1) {
    int x = (t >= off) ? sm[t - off] : 0;
    __syncthreads();
    sm[t] += x;
    __syncthreads();
  }
  int run = p0 + sm[t] - s;
  int r0 = run, r1 = run + v0, r2 = r1 + v1, r3 = r2 + v2;
  h[4 * t] = r0; h[4 * t + 1] = r1; h[4 * t + 2] = r2; h[4 * t + 3] = r3;
  if (4 * t + 0 < nn) { cnt[base + 4*t+0] = v0; dis[base + 4*t+0] = rsqrtf((float)v0 + 1.f); rs[base + 4*t+0] = r0; }
  if (4 * t + 1 < nn) { cnt[base + 4*t+1] = v1; dis[base + 4*t+1] = rsqrtf((float)v1 + 1.f); rs[base + 4*t+1] = r1; }
  if (4 * t + 2 < nn) { cnt[base + 4*t+2] = v2; dis[base + 4*t+2] = rsqrtf((float)v2 + 1.f); rs[base + 4*t+2] = r2; }
  if (4 * t + 3 < nn) { cnt[base + 4*t+3] = v3; dis[base + 4*t+3] = rsqrtf((float)v3 + 1.f); rs[base + 4*t+3] = r3; }
  __syncthreads();

  if (srt) {
    // counting sort of buf by src-bin (src>>8, < 512 bins) into buf2
    for (int i = t; i < 512; i += 256) sh[i] = 0;
    __syncthreads();
    for (int i = t; i < ne; i += 256)
      atomicAdd(&sh[(buf[i] & smask) >> 8], 1);
    __syncthreads();
    int a0 = sh[2 * t], a1 = sh[2 * t + 1];
    int ss = a0 + a1;
    sm[t] = ss;
    __syncthreads();
    for (int off = 1; off < 256; off <<= 1) {
      int x = (t >= off) ? sm[t - off] : 0;
      __syncthreads();
      sm[t] += x;
      __syncthreads();
    }
    int rn = sm[t] - ss;
    sh[2 * t] = rn; sh[2 * t + 1] = rn + a0;
    __syncthreads();
    for (int i = t; i < ne; i += 256) {
      unsigned p = buf[i];
      int pos = atomicAdd(&sh[(p & smask) >> 8], 1);
      buf2[pos] = p;
    }
    __syncthreads();
    // scatter (approx src-ascending) into final CSR via dst cursors
    for (int i = t; i < ne; i += 256) {
      unsigned p = buf2[i];
      int pos = atomicAdd(&h[p >> SB], 1);
      csr[pos] = (int)(p & smask);
    }
  } else {
    for (int i = p0 + t; i < p1; i += 256) {
      unsigned p = pairs[i];
      int pos = atomicAdd(&h[p >> SB], 1);
      csr[pos] = (int)(p & smask);
    }
  }
}

__global__ __launch_bounds__(1024) void k_scan1(const int* __restrict__ cnt,
                                                int* __restrict__ bsums, int n) {
  __shared__ int sm[1024];
  int t = threadIdx.x;
  long i = (long)blockIdx.x * 1024 + t;
  sm[t] = (i < n) ? cnt[i] : 0;
  __syncthreads();
  for (int s = 512; s > 0; s >>= 1) {
    if (t < s) sm[t] += sm[t + s];
    __syncthreads();
  }
  if (t == 0) bsums[blockIdx.x] = sm[0];
}

__global__ void k_scan2(int* __restrict__ bsums, int nb) {
  __shared__ int sm[128];
  int t = threadIdx.x;
  int v = (t < nb) ? bsums[t] : 0;
  sm[t] = v;
  __syncthreads();
  for (int off = 1; off < 128; off <<= 1) {
    int x = (t >= off) ? sm[t - off] : 0;
    __syncthreads();
    sm[t] += x;
    __syncthreads();
  }
  if (t < nb) bsums[t] = sm[t] - v;  // exclusive
}

// exclusive scan -> out (may alias in); optional sentinel out[n] = total.
__global__ __launch_bounds__(1024) void k_scan3s(const int* __restrict__ in,
                                                 const int* __restrict__ bsums,
                                                 int* __restrict__ out, int n,
                                                 int sentinel) {
  __shared__ int sm[1024];
  int t = threadIdx.x;
  long i = (long)blockIdx.x * 1024 + t;
  int v = (i < n) ? in[i] : 0;
  sm[t] = v;
  __syncthreads();
  for (int off = 1; off < 1024; off <<= 1) {
    int x = (t >= off) ? sm[t - off] : 0;
    __syncthreads();
    sm[t] += x;
    __syncthreads();
  }
  int excl = sm[t] - v + bsums[blockIdx.x];
  if (i < n) out[i] = excl;
  if (sentinel && i == n - 1) out[n] = excl + v;
}

__device__ __forceinline__ float bfu(unsigned short u) {
  return __uint_as_float((unsigned)u << 16);
}
__device__ __forceinline__ float bf_lo(unsigned u) {
  return __uint_as_float(u << 16);
}
__device__ __forceinline__ float bf_hi(unsigned u) {
  return __uint_as_float(u & 0xffff0000u);
}
__device__ __forceinline__ unsigned pack_bf2(float lo, float hi) {
  __hip_bfloat16 a = __float2bfloat16(lo), b = __float2bfloat16(hi);
  return (unsigned)*(unsigned short*)&a | ((unsigned)*(unsigned short*)&b << 16);
}

// C[n, M] = act(A[n, K] @ W[K, M] (+ bias)); W row-major [K][M], staged in LDS.
// K-loop pinned to no-unroll + manual next-k prefetch.
// ABF16: A rows are bf16. OBF16: write output as bf16 (RNE).
template <int K, int M, bool BIAS, int ACT, bool ABF16, bool OBF16>
__global__ __launch_bounds__(256) void k_gemm(const void* __restrict__ Av,
                                              const float* __restrict__ W,
                                              const float* __restrict__ bias,
                                              void* __restrict__ Cout, int nrows) {
  constexpr int CP = 4;
  constexpr int TPR = M / CP;        // threads per row
  constexpr int RG = 256 / TPR;      // row-groups per block
  constexpr int RP = 4;              // rows per thread
  constexpr int RT = RG * RP;        // rows per block
  __shared__ __align__(16) float sW[K * M];
  __shared__ __align__(16) float sB[BIAS ? M : 4];

  for (int i = threadIdx.x; i < K * M / 4; i += 256)
    ((float4*)sW)[i] = ((const float4*)W)[i];
  if (BIAS)
    for (int i = threadIdx.x; i < M; i += 256) sB[i] = bias[i];
  __syncthreads();

  const int cg = threadIdx.x % TPR;
  const int rg = threadIdx.x / TPR;
  const long row0 = (long)blockIdx.x * RT + rg;

  const float4* Apf[RP];
  const ushort4* Apb[RP];
  bool valid[RP];
#pragma unroll
  for (int r = 0; r < RP; ++r) {
    long row = row0 + (long)r * RG;
    valid[r] = (row < nrows);
    long rr = valid[r] ? row : 0;
    if (ABF16) Apb[r] = (const ushort4*)((const unsigned short*)Av + rr * K);
    else       Apf[r] = (const float4*)((const float*)Av + rr * K);
  }

  auto loadA = [&](int r, int k4) -> float4 {
    if (!valid[r]) return make_float4(0.f, 0.f, 0.f, 0.f);
    if (ABF16) {
      ushort4 q = Apb[r][k4];
      return make_float4(bfu(q.x), bfu(q.y), bfu(q.z), bfu(q.w));
    }
    return Apf[r][k4];
  };

  float acc[RP][CP] = {};
  float4 a[RP];
#pragma unroll
  for (int r = 0; r < RP; ++r) a[r] = loadA(r, 0);

#pragma unroll 1
  for (int k0 = 0; k0 < K - 4; k0 += 4) {
    float4 an[RP];
#pragma unroll
    for (int r = 0; r < RP; ++r) an[r] = loadA(r, k0 / 4 + 1);
#pragma unroll
    for (int j = 0; j < 4; ++j) {
      float4 w = ((const float4*)(sW + (k0 + j) * M))[cg];
#pragma unroll
      for (int r = 0; r < RP; ++r) {
        float av = (j == 0) ? a[r].x : (j == 1) ? a[r].y : (j == 2) ? a[r].z : a[r].w;
        acc[r][0] += av * w.x;
        acc[r][1] += av * w.y;
        acc[r][2] += av * w.z;
        acc[r][3] += av * w.w;
      }
    }
#pragma unroll
    for (int r = 0; r < RP; ++r) a[r] = an[r];
  }
  {  // last k-step
    const int k0 = K - 4;
#pragma unroll
    for (int j = 0; j < 4; ++j) {
      float4 w = ((const float4*)(sW + (k0 + j) * M))[cg];
#pragma unroll
      for (int r = 0; r < RP; ++r) {
        float av = (j == 0) ? a[r].x : (j == 1) ? a[r].y : (j == 2) ? a[r].z : a[r].w;
        acc[r][0] += av * w.x;
        acc[r][1] += av * w.y;
        acc[r][2] += av * w.z;
        acc[r][3] += av * w.w;
      }
    }
  }

#pragma unroll
  for (int r = 0; r < RP; ++r) {
    long row = row0 + (long)r * RG;
    if (row >= nrows) continue;
    float4 o = make_float4(acc[r][0], acc[r][1], acc[r][2], acc[r][3]);
    if (BIAS) {
      float4 bb = ((const float4*)sB)[cg];
      o.x += bb.x; o.y += bb.y; o.z += bb.z; o.w += bb.w;
    }
    if (ACT == 1) {
      o.x = fmaxf(o.x, 0.f); o.y = fmaxf(o.y, 0.f);
      o.z = fmaxf(o.z, 0.f); o.w = fmaxf(o.w, 0.f);
    }
    if (OBF16) {
      uint2 pk;
      pk.x = pack_bf2(o.x, o.y);
      pk.y = pack_bf2(o.z, o.w);
      ((uint2*)((__hip_bfloat16*)Cout + row * M))[cg] = pk;
    } else {
      ((float4*)((float*)Cout + row * M))[cg] = o;
    }
  }
}

// Windowed pull agg, D=64 bf16: 16 lanes/node (uint2 = 4 feats per lane),
// each 16-lane group owns 4 consecutive nodes; all slots co-resident sweep
// the src table window-by-window (lists ~src-sorted). Any order is correct:
// each edge processed exactly once (window check only delays processing).
__global__ __launch_bounds__(256) void k_agg64w(const uint2* __restrict__ hw,
                                                const int* __restrict__ csr,
                                                const int* __restrict__ rs,
                                                const int* __restrict__ cnt,
                                                const float* __restrict__ dis,
                                                const float* __restrict__ b,
                                                uint2* __restrict__ out, int n,
                                                int NW, int WS) {
  unsigned slot = blockIdx.x * 16u + (threadIdx.x >> 4);
  unsigned f4 = threadIdx.x & 15u;
  unsigned n0 = slot * 4u;
  if (n0 >= (unsigned)n) return;
  int nm = min(4, n - (int)n0);
  float acc[4][4];
  int c[4], ee[4];
  float dsn[4];
#pragma unroll
  for (int m = 0; m < 4; ++m) {
    if (m < nm) {
      unsigned nd = n0 + m;
      dsn[m] = dis[nd];
      c[m] = rs[nd];
      ee[m] = c[m] + cnt[nd];
      uint2 su = hw[nd * 16u + f4];
      float d2 = dsn[m] * dsn[m];
      acc[m][0] = bf_lo(su.x) * d2; acc[m][1] = bf_hi(su.x) * d2;
      acc[m][2] = bf_lo(su.y) * d2; acc[m][3] = bf_hi(su.y) * d2;
    } else {
      c[m] = 0; ee[m] = 0; dsn[m] = 0.f;
      acc[m][0] = acc[m][1] = acc[m][2] = acc[m][3] = 0.f;
    }
  }
  for (int w = 1; w <= NW; ++w) {
    int winEnd = (w == NW) ? 0x7FFFFFFF : w * WS;
#pragma unroll
    for (int m = 0; m < 4; ++m) {
      int cc = c[m];
      const int e1 = ee[m];
      const float dn = dsn[m];
      while (cc + 4 <= e1) {
        int s0 = csr[cc], s1 = csr[cc + 1], s2 = csr[cc + 2], s3 = csr[cc + 3];
        if (s3 >= winEnd) break;
        float w0 = dis[s0] * dn, w1 = dis[s1] * dn;
        float w2 = dis[s2] * dn, w3 = dis[s3] * dn;
        uint2 u0 = hw[(unsigned)s0 * 16u + f4];
        uint2 u1 = hw[(unsigned)s1 * 16u + f4];
        uint2 u2 = hw[(unsigned)s2 * 16u + f4];
        uint2 u3 = hw[(unsigned)s3 * 16u + f4];
        acc[m][0] += bf_lo(u0.x) * w0 + bf_lo(u1.x) * w1 + bf_lo(u2.x) * w2 + bf_lo(u3.x) * w3;
        acc[m][1] += bf_hi(u0.x) * w0 + bf_hi(u1.x) * w1 + bf_hi(u2.x) * w2 + bf_hi(u3.x) * w3;
        acc[m][2] += bf_lo(u0.y) * w0 + bf_lo(u1.y) * w1 + bf_lo(u2.y) * w2 + bf_lo(u3.y) * w3;
        acc[m][3] += bf_hi(u0.y) * w0 + bf_hi(u1.y) * w1 + bf_hi(u2.y) * w2 + bf_hi(u3.y) * w3;
        cc += 4;
      }
      while (cc < e1) {
        int s0 = csr[cc];
        if (s0 >= winEnd) break;
        float w0 = dis[s0] * dn;
        uint2 u0 = hw[(unsigned)s0 * 16u + f4];
        acc[m][0] += bf_lo(u0.x) * w0;
        acc[m][1] += bf_hi(u0.x) * w0;
        acc[m][2] += bf_lo(u0.y) * w0;
        acc[m][3] += bf_hi(u0.y) * w0;
        ++cc;
      }
      c[m] = cc;
    }
  }
  float4 bb = ((const float4*)b)[f4];
#pragma unroll
  for (int m = 0; m < 4; ++m) {
    if (m < nm) {
      unsigned nd = n0 + m;
      uint2 pk;
      pk.x = pack_bf2(fmaxf(acc[m][0] + bb.x, 0.f), fmaxf(acc[m][1] + bb.y, 0.f));
      pk.y = pack_bf2(fmaxf(acc[m][2] + bb.z, 0.f), fmaxf(acc[m][3] + bb.w, 0.f));
      out[nd * 16u + f4] = pk;
    }
  }
}

// Windowed pull agg, D=32 bf16: 8 lanes/node, 4 consecutive nodes per group.
// fp32 output (this IS the h output in d_out).
__global__ __launch_bounds__(256) void k_agg32w(const uint2* __restrict__ hw,
                                                const int* __restrict__ csr,
                                                const int* __restrict__ rs,
                                                const int* __restrict__ cnt,
                                                const float* __restrict__ dis,
                                                const float* __restrict__ b,
                                                float* __restrict__ out, int n,
                                                int NW, int WS) {
  unsigned slot = blockIdx.x * 32u + (threadIdx.x >> 3);
  unsigned f4 = threadIdx.x & 7u;
  unsigned n0 = slot * 4u;
  if (n0 >= (unsigned)n) return;
  int nm = min(4, n - (int)n0);
  float acc[4][4];
  int c[4], ee[4];
  float dsn[4];
#pragma unroll
  for (int m = 0; m < 4; ++m) {
    if (m < nm) {
      unsigned nd = n0 + m;
      dsn[m] = dis[nd];
      c[m] = rs[nd];
      ee[m] = c[m] + cnt[nd];
      uint2 su = hw[nd * 8u + f4];
      float d2 = dsn[m] * dsn[m];
      acc[m][0] = bf_lo(su.x) * d2; acc[m][1] = bf_hi(su.x) * d2;
      acc[m][2] = bf_lo(su.y) * d2; acc[m][3] = bf_hi(su.y) * d2;
    } else {
      c[m] = 0; ee[m] = 0; dsn[m] = 0.f;
      acc[m][0] = acc[m][1] = acc[m][2] = acc[m][3] = 0.f;
    }
  }
  for (int w = 1; w <= NW; ++w) {
    int winEnd = (w == NW) ? 0x7FFFFFFF : w * WS;
#pragma unroll
    for (int m = 0; m < 4; ++m) {
      int cc = c[m];
      const int e1 = ee[m];
      const float dn = dsn[m];
      while (cc + 4 <= e1) {
        int s0 = csr[cc], s1 = csr[cc + 1], s2 = csr[cc + 2], s3 = csr[cc + 3];
        if (s3 >= winEnd) break;
        float w0 = dis[s0] * dn, w1 = dis[s1] * dn;
        float w2 = dis[s2] * dn, w3 = dis[s3] * dn;
        uint2 u0 = hw[(unsigned)s0 * 8u + f4];
        uint2 u1 = hw[(unsigned)s1 * 8u + f4];
        uint2 u2 = hw[(unsigned)s2 * 8u + f4];
        uint2 u3 = hw[(unsigned)s3 * 8u + f4];
        acc[m][0] += bf_lo(u0.x) * w0 + bf_lo(u1.x) * w1 + bf_lo(u2.x) * w2 + bf_lo(u3.x) * w3;
        acc[m][1] += bf_hi(u0.x) * w0 + bf_hi(u1.x) * w1 + bf_hi(u2.x) * w2 + bf_hi(u3.x) * w3;
        acc[m][2] += bf_lo(u0.y) * w0 + bf_lo(u1.y) * w1 + bf_lo(u2.y) * w2 + bf_lo(u3.y) * w3;
        acc[m][3] += bf_hi(u0.y) * w0 + bf_hi(u1.y) * w1 + bf_hi(u2.y) * w2 + bf_hi(u3.y) * w3;
        cc += 4;
      }
      while (cc < e1) {
        int s0 = csr[cc];
        if (s0 >= winEnd) break;
        float w0 = dis[s0] * dn;
        uint2 u0 = hw[(unsigned)s0 * 8u + f4];
        acc[m][0] += bf_lo(u0.x) * w0;
        acc[m][1] += bf_hi(u0.x) * w0;
        acc[m][2] += bf_lo(u0.y) * w0;
        acc[m][3] += bf_hi(u0.y) * w0;
        ++cc;
      }
      c[m] = cc;
    }
  }
  float4 bb = ((const float4*)b)[f4];
#pragma unroll
  for (int m = 0; m < 4; ++m) {
    if (m < nm) {
      unsigned nd = n0 + m;
      ((float4*)(out + nd * 32u))[f4] =
          make_float4(acc[m][0] + bb.x, acc[m][1] + bb.y,
                      acc[m][2] + bb.z, acc[m][3] + bb.w);
    }
  }
}

// score = sigmoid(s[N,32] @ sW2[32] + sb2); 8 nodes per 256-thread block.
__global__ void k_score(const float* __restrict__ s, const float* __restrict__ sW2,
                        const float* __restrict__ sb2, float* __restrict__ out, int n) {
  int node = blockIdx.x * 8 + (threadIdx.x >> 5);
  int k = threadIdx.x & 31;
  if (node >= n) return;
  float v = s[(long)node * 32 + k] * sW2[k];
  for (int off = 16; off > 0; off >>= 1) v += __shfl_down(v, off, 32);
  if (k == 0) out[node] = 1.0f / (1.0f + expf(-(v + sb2[0])));
}

extern "C" void kernel_launch(void* const* d_in, const int* in_sizes, int n_in,
                              void* d_out, int out_size, void* d_ws, size_t ws_size,
                              hipStream_t stream) {
  const float* x   = (const float*)d_in[0];
  const void*  ei  = d_in[1];
  const float* W1  = (const float*)d_in[2];
  const float* b1  = (const float*)d_in[3];
  const float* W2  = (const float*)d_in[4];
  const float* b2  = (const float*)d_in[5];
  const float* rW1 = (const float*)d_in[6];
  const float* rb1 = (const float*)d_in[7];
  const float* rW2 = (const float*)d_in[8];
  const float* rb2 = (const float*)d_in[9];
  const float* sW1 = (const float*)d_in[10];
  const float* sb1 = (const float*)d_in[11];
  const float* sW2 = (const float*)d_in[12];
  const float* sb2 = (const float*)d_in[13];

  const int N = in_sizes[0] / 128;
  const int E = in_sizes[1] / 2;

  // bucket geometry: SPB = 1<<shift nodes per bucket, B buckets (<=256)
  int shift = 9;
  while ((((long)N + (1L << shift) - 1) >> shift) > 256) ++shift;
  const int SB = 32 - shift;               // src bits in packed pair (N < 2^SB here)
  const int B = (int)(((long)N + (1L << shift) - 1) >> shift);
  const int C = 512;                       // edge chunks
  const int CS = (E + C - 1) / C;          // edges per chunk
  const int L = B * C;

  // workspace layout (256B aligned chunks)
  char* w = (char*)d_ws;
  auto alloc = [&](size_t bytes) {
    char* p = w;
    w += (bytes + 255) & ~(size_t)255;
    return p;
  };
  int*   meta   = (int*)alloc(64);
  int*   cnt    = (int*)alloc((size_t)N * 4);
  int*   rs     = (int*)alloc((size_t)N * 4);
  float* dis    = (float*)alloc((size_t)N * 4);
  int*   bsumsL = (int*)alloc(1024);
  int*   bscan  = (int*)alloc(((size_t)L + 1) * 4);
  int*   csr    = (int*)alloc((size_t)E * 4);
  // union buffer: pairs (E*4B packed) -> later tbuf bf16 [N,64] / sbuf fp32 [N,32]
  size_t uni = (size_t)E * 4 > (size_t)N * 128 ? (size_t)E * 4 : (size_t)N * 128;
  char*  u      = alloc(uni);
  unsigned* pairs = (unsigned*)u;
  __hip_bfloat16* tbuf = (__hip_bfloat16*)u;   // recon intermediate [N,64] bf16
  float* sbuf   = (float*)u;                   // scorer intermediate [N,32] fp32
  uint2* hw1 = (uint2*)alloc((size_t)N * 64 * 2);  // bf16 [N][64]
  uint2* h1  = (uint2*)alloc((size_t)N * 64 * 2);  // bf16 [N][64]
  uint2* hw2 = (uint2*)alloc((size_t)N * 32 * 2);  // bf16 [N][32]

  float* h_out = (float*)d_out;                 // [N,32]
  float* x_rec = h_out + (long)N * 32;          // [N,128]
  float* score = x_rec + (long)N * 128;         // [N,1]

  // ---- CSR build (atomic-free two-level counting sort, src-sorted lists) ----
  k_detect<<<1, 256, 0, stream>>>((const unsigned int*)ei, E < 4096 ? E : 4096, meta);
  k_binhist<<<C, 256, 0, stream>>>(ei, E, CS, B, shift, meta, bscan, C);
  int nbL = (L + 1023) / 1024;
  k_scan1<<<nbL, 1024, 0, stream>>>(bscan, bsumsL, L);
  k_scan2<<<1, 128, 0, stream>>>(bsumsL, nbL);
  k_scan3s<<<nbL, 1024, 0, stream>>>(bscan, bsumsL, bscan, L, 1);  // in-place + sentinel
  k_binscatter<<<C, 256, 0, stream>>>(ei, E, CS, B, shift, SB, meta, bscan, C, pairs);
  k_bucketbuild<<<B, 256, 0, stream>>>(pairs, bscan, C, shift, SB, N, cnt, dis, rs, csr);

  // windowed sweep geometry
  const int WS64 = 4096, NW64 = (N + WS64 - 1) / WS64;
  const int WS32 = 8192, NW32 = (N + WS32 - 1) / WS32;

  // ---- layer 1: hw1 = bf16(x @ W1) ; h1 = bf16(relu(agg + b1)) ----
  k_gemm<128, 64, false, 0, false, true><<<(N + 63) / 64, 256, 0, stream>>>(x, W1, nullptr, hw1, N);
  k_agg64w<<<(N + 63) / 64, 256, 0, stream>>>(hw1, csr, rs, cnt, dis, b1, h1, N, NW64, WS64);

  // ---- layer 2: hw2 = bf16(h1 @ W2) ; h = agg + b2 -> d_out ----
  k_gemm<64, 32, false, 0, true, true><<<(N + 127) / 128, 256, 0, stream>>>(h1, W2, nullptr, hw2, N);
  k_agg32w<<<(N + 127) / 128, 256, 0, stream>>>(hw2, csr, rs, cnt, dis, b2, h_out, N, NW32, WS32);

  // ---- reconstruction MLP: t = bf16(relu(h@rW1+rb1)) ; x_rec = t@rW2+rb2 ----
  k_gemm<32, 64, true, 1, false, true><<<(N + 63) / 64, 256, 0, stream>>>(h_out, rW1, rb1, tbuf, N);
  k_gemm<64, 128, true, 0, true, false><<<(N + 31) / 32, 256, 0, stream>>>(tbuf, rW2, rb2, x_rec, N);

  // ---- scorer MLP: s = relu(h@sW1+sb1) ; score = sigmoid(s@sW2+sb2) ----
  k_gemm<32, 32, true, 1, false, false><<<(N + 127) / 128, 256, 0, stream>>>(h_out, sW1, sb1, sbuf, N);
  k_score<<<(N + 7) / 8, 256, 0, stream>>>(sbuf, sW2, sb2, score, N);
}

// Round 10
// 332.696 us; speedup vs baseline: 1.8509x; 1.8509x over previous
//
#include <hip/hip_runtime.h>
#include <hip/hip_bf16.h>
#include <math.h>

// ---------------------------------------------------------------------------
// GCN anomaly detector.
// Round 9 fix: windowed walkers cut agg FETCH 167->66MB (locality theory
// confirmed) but serialized execution (1.3 edges/node/window -> scalar tail
// + branch per edge, 244us). Round 10: keep the src-sorted CSR (free at agg
// time), revert aggs to the round-8 high-MLP structure (uint2/lane, unroll
// 8). Co-resident waves walking sorted lists at similar rates produce a
// PASSIVE coherent sweep of the feature table -- locality without windows.
// ---------------------------------------------------------------------------

__global__ void k_detect(const unsigned int* __restrict__ w, int npairs,
                         int* __restrict__ meta) {
  __shared__ int any;
  if (threadIdx.x == 0) any = 0;
  __syncthreads();
  int local = 0;
  for (int i = threadIdx.x; i < npairs; i += blockDim.x)
    local |= (w[2 * i + 1] != 0u);
  if (local) atomicOr(&any, 1);
  __syncthreads();
  if (threadIdx.x == 0) meta[0] = any ? 0 : 1;  // 1 => edge_index is int64
}

// P1: per-chunk LDS histogram over dst buckets. hist layout: [bin][chunk].
__global__ __launch_bounds__(256) void k_binhist(const void* __restrict__ ei,
                                                 int E, int CS, int B, int shift,
                                                 const int* __restrict__ meta,
                                                 int* __restrict__ hist, int C) {
  __shared__ int lh[256];
  int c = blockIdx.x;
  for (int i = threadIdx.x; i < B; i += 256) lh[i] = 0;
  __syncthreads();
  int e0 = c * CS, e1 = min(E, e0 + CS);
  bool is64 = meta[0] != 0;
  for (int e = e0 + threadIdx.x; e < e1; e += 256) {
    int d = is64 ? (int)((const long long*)ei)[(long)E + e]
                 : ((const int*)ei)[(long)E + e];
    atomicAdd(&lh[d >> shift], 1);
  }
  __syncthreads();
  for (int b = threadIdx.x; b < B; b += 256) hist[(long)b * C + c] = lh[b];
}

// P3: re-read edges, write packed (dstInBucket<<SB | src) into reserved
// per-(chunk,bin) ranges. LDS cursors only -> zero global atomics.
__global__ __launch_bounds__(256) void k_binscatter(const void* __restrict__ ei,
                                                    int E, int CS, int B, int shift,
                                                    int SB,
                                                    const int* __restrict__ meta,
                                                    const int* __restrict__ scan,
                                                    int C, unsigned* __restrict__ pairs) {
  __shared__ int cur[256];
  int c = blockIdx.x;
  for (int b = threadIdx.x; b < B; b += 256) cur[b] = scan[(long)b * C + c];
  __syncthreads();
  int e0 = c * CS, e1 = min(E, e0 + CS);
  bool is64 = meta[0] != 0;
  unsigned spb1 = (1u << shift) - 1u;
  for (int e = e0 + threadIdx.x; e < e1; e += 256) {
    int s, d;
    if (is64) {
      const long long* p = (const long long*)ei;
      s = (int)p[e]; d = (int)p[(long)E + e];
    } else {
      const int* p = (const int*)ei;
      s = p[e]; d = p[(long)E + e];
    }
    int pos = atomicAdd(&cur[d >> shift], 1);
    pairs[pos] = (((unsigned)d & spb1) << SB) | (unsigned)s;
  }
}

// P4 (fused): per-bucket degree hist -> cnt, dis, rs; then in-LDS counting
// sort by src-bin (src>>8) so each dst's CSR list comes out ~src-ascending;
// scatter via LDS cursors. Overflow falls back to unsorted (still correct).
#define BB_CAP 16896
__global__ __launch_bounds__(256) void k_bucketbuild(const unsigned* __restrict__ pairs,
                                                     const int* __restrict__ scan,
                                                     int C, int shift, int SB, int N,
                                                     int* __restrict__ cnt,
                                                     float* __restrict__ dis,
                                                     int* __restrict__ rs,
                                                     int* __restrict__ csr) {
  __shared__ unsigned buf[BB_CAP];    // 66 KB
  __shared__ unsigned buf2[BB_CAP];   // 66 KB
  __shared__ int h[1024];
  __shared__ int sm[256];
  __shared__ int sh[512];
  int bin = blockIdx.x;
  int base = bin << shift;
  int nn = min(N - base, 1 << shift);
  int t = threadIdx.x;
  unsigned smask = (1u << SB) - 1u;
  int p0 = scan[(long)bin * C];
  int p1 = scan[(long)(bin + 1) * C];  // sentinel row gives E for last bucket
  int ne = p1 - p0;
  bool srt = (ne <= BB_CAP);

  if (srt)
    for (int i = t; i < ne; i += 256) buf[i] = pairs[p0 + i];
  for (int i = t; i < 1024; i += 256) h[i] = 0;
  __syncthreads();

  for (int i = t; i < ne; i += 256)
    atomicAdd(&h[(srt ? buf[i] : pairs[p0 + i]) >> SB], 1);
  __syncthreads();

  int v0 = h[4 * t], v1 = h[4 * t + 1], v2 = h[4 * t + 2], v3 = h[4 * t + 3];
  int s = v0 + v1 + v2 + v3;
  sm[t] = s;
  __syncthreads();
  for (int off = 1; off < 256; off <<= 1) {
    int x = (t >= off) ? sm[t - off] : 0;
    __syncthreads();
    sm[t] += x;
    __syncthreads();
  }
  int run = p0 + sm[t] - s;
  int r0 = run, r1 = run + v0, r2 = r1 + v1, r3 = r2 + v2;
  h[4 * t] = r0; h[4 * t + 1] = r1; h[4 * t + 2] = r2; h[4 * t + 3] = r3;
  if (4 * t + 0 < nn) { cnt[base + 4*t+0] = v0; dis[base + 4*t+0] = rsqrtf((float)v0 + 1.f); rs[base + 4*t+0] = r0; }
  if (4 * t + 1 < nn) { cnt[base + 4*t+1] = v1; dis[base + 4*t+1] = rsqrtf((float)v1 + 1.f); rs[base + 4*t+1] = r1; }
  if (4 * t + 2 < nn) { cnt[base + 4*t+2] = v2; dis[base + 4*t+2] = rsqrtf((float)v2 + 1.f); rs[base + 4*t+2] = r2; }
  if (4 * t + 3 < nn) { cnt[base + 4*t+3] = v3; dis[base + 4*t+3] = rsqrtf((float)v3 + 1.f); rs[base + 4*t+3] = r3; }
  __syncthreads();

  if (srt) {
    // counting sort by src-bin (src>>8, < 512 bins) into buf2
    for (int i = t; i < 512; i += 256) sh[i] = 0;
    __syncthreads();
    for (int i = t; i < ne; i += 256)
      atomicAdd(&sh[(buf[i] & smask) >> 8], 1);
    __syncthreads();
    int a0 = sh[2 * t], a1 = sh[2 * t + 1];
    int ss = a0 + a1;
    sm[t] = ss;
    __syncthreads();
    for (int off = 1; off < 256; off <<= 1) {
      int x = (t >= off) ? sm[t - off] : 0;
      __syncthreads();
      sm[t] += x;
      __syncthreads();
    }
    int rn = sm[t] - ss;
    sh[2 * t] = rn; sh[2 * t + 1] = rn + a0;
    __syncthreads();
    for (int i = t; i < ne; i += 256) {
      unsigned p = buf[i];
      int pos = atomicAdd(&sh[(p & smask) >> 8], 1);
      buf2[pos] = p;
    }
    __syncthreads();
    for (int i = t; i < ne; i += 256) {
      unsigned p = buf2[i];
      int pos = atomicAdd(&h[p >> SB], 1);
      csr[pos] = (int)(p & smask);
    }
  } else {
    for (int i = p0 + t; i < p1; i += 256) {
      unsigned p = pairs[i];
      int pos = atomicAdd(&h[p >> SB], 1);
      csr[pos] = (int)(p & smask);
    }
  }
}

__global__ __launch_bounds__(1024) void k_scan1(const int* __restrict__ cnt,
                                                int* __restrict__ bsums, int n) {
  __shared__ int sm[1024];
  int t = threadIdx.x;
  long i = (long)blockIdx.x * 1024 + t;
  sm[t] = (i < n) ? cnt[i] : 0;
  __syncthreads();
  for (int s = 512; s > 0; s >>= 1) {
    if (t < s) sm[t] += sm[t + s];
    __syncthreads();
  }
  if (t == 0) bsums[blockIdx.x] = sm[0];
}

__global__ void k_scan2(int* __restrict__ bsums, int nb) {
  __shared__ int sm[128];
  int t = threadIdx.x;
  int v = (t < nb) ? bsums[t] : 0;
  sm[t] = v;
  __syncthreads();
  for (int off = 1; off < 128; off <<= 1) {
    int x = (t >= off) ? sm[t - off] : 0;
    __syncthreads();
    sm[t] += x;
    __syncthreads();
  }
  if (t < nb) bsums[t] = sm[t] - v;  // exclusive
}

// exclusive scan -> out (may alias in); optional sentinel out[n] = total.
__global__ __launch_bounds__(1024) void k_scan3s(const int* __restrict__ in,
                                                 const int* __restrict__ bsums,
                                                 int* __restrict__ out, int n,
                                                 int sentinel) {
  __shared__ int sm[1024];
  int t = threadIdx.x;
  long i = (long)blockIdx.x * 1024 + t;
  int v = (i < n) ? in[i] : 0;
  sm[t] = v;
  __syncthreads();
  for (int off = 1; off < 1024; off <<= 1) {
    int x = (t >= off) ? sm[t - off] : 0;
    __syncthreads();
    sm[t] += x;
    __syncthreads();
  }
  int excl = sm[t] - v + bsums[blockIdx.x];
  if (i < n) out[i] = excl;
  if (sentinel && i == n - 1) out[n] = excl + v;
}

__device__ __forceinline__ float bfu(unsigned short u) {
  return __uint_as_float((unsigned)u << 16);
}
__device__ __forceinline__ float bf_lo(unsigned u) {
  return __uint_as_float(u << 16);
}
__device__ __forceinline__ float bf_hi(unsigned u) {
  return __uint_as_float(u & 0xffff0000u);
}
__device__ __forceinline__ unsigned pack_bf2(float lo, float hi) {
  __hip_bfloat16 a = __float2bfloat16(lo), b = __float2bfloat16(hi);
  return (unsigned)*(unsigned short*)&a | ((unsigned)*(unsigned short*)&b << 16);
}

// C[n, M] = act(A[n, K] @ W[K, M] (+ bias)); W row-major [K][M], staged in LDS.
// K-loop pinned to no-unroll + manual next-k prefetch.
// ABF16: A rows are bf16. OBF16: write output as bf16 (RNE).
template <int K, int M, bool BIAS, int ACT, bool ABF16, bool OBF16>
__global__ __launch_bounds__(256) void k_gemm(const void* __restrict__ Av,
                                              const float* __restrict__ W,
                                              const float* __restrict__ bias,
                                              void* __restrict__ Cout, int nrows) {
  constexpr int CP = 4;
  constexpr int TPR = M / CP;        // threads per row
  constexpr int RG = 256 / TPR;      // row-groups per block
  constexpr int RP = 4;              // rows per thread
  constexpr int RT = RG * RP;        // rows per block
  __shared__ __align__(16) float sW[K * M];
  __shared__ __align__(16) float sB[BIAS ? M : 4];

  for (int i = threadIdx.x; i < K * M / 4; i += 256)
    ((float4*)sW)[i] = ((const float4*)W)[i];
  if (BIAS)
    for (int i = threadIdx.x; i < M; i += 256) sB[i] = bias[i];
  __syncthreads();

  const int cg = threadIdx.x % TPR;
  const int rg = threadIdx.x / TPR;
  const long row0 = (long)blockIdx.x * RT + rg;

  const float4* Apf[RP];
  const ushort4* Apb[RP];
  bool valid[RP];
#pragma unroll
  for (int r = 0; r < RP; ++r) {
    long row = row0 + (long)r * RG;
    valid[r] = (row < nrows);
    long rr = valid[r] ? row : 0;
    if (ABF16) Apb[r] = (const ushort4*)((const unsigned short*)Av + rr * K);
    else       Apf[r] = (const float4*)((const float*)Av + rr * K);
  }

  auto loadA = [&](int r, int k4) -> float4 {
    if (!valid[r]) return make_float4(0.f, 0.f, 0.f, 0.f);
    if (ABF16) {
      ushort4 q = Apb[r][k4];
      return make_float4(bfu(q.x), bfu(q.y), bfu(q.z), bfu(q.w));
    }
    return Apf[r][k4];
  };

  float acc[RP][CP] = {};
  float4 a[RP];
#pragma unroll
  for (int r = 0; r < RP; ++r) a[r] = loadA(r, 0);

#pragma unroll 1
  for (int k0 = 0; k0 < K - 4; k0 += 4) {
    float4 an[RP];
#pragma unroll
    for (int r = 0; r < RP; ++r) an[r] = loadA(r, k0 / 4 + 1);
#pragma unroll
    for (int j = 0; j < 4; ++j) {
      float4 w = ((const float4*)(sW + (k0 + j) * M))[cg];
#pragma unroll
      for (int r = 0; r < RP; ++r) {
        float av = (j == 0) ? a[r].x : (j == 1) ? a[r].y : (j == 2) ? a[r].z : a[r].w;
        acc[r][0] += av * w.x;
        acc[r][1] += av * w.y;
        acc[r][2] += av * w.z;
        acc[r][3] += av * w.w;
      }
    }
#pragma unroll
    for (int r = 0; r < RP; ++r) a[r] = an[r];
  }
  {  // last k-step
    const int k0 = K - 4;
#pragma unroll
    for (int j = 0; j < 4; ++j) {
      float4 w = ((const float4*)(sW + (k0 + j) * M))[cg];
#pragma unroll
      for (int r = 0; r < RP; ++r) {
        float av = (j == 0) ? a[r].x : (j == 1) ? a[r].y : (j == 2) ? a[r].z : a[r].w;
        acc[r][0] += av * w.x;
        acc[r][1] += av * w.y;
        acc[r][2] += av * w.z;
        acc[r][3] += av * w.w;
      }
    }
  }

#pragma unroll
  for (int r = 0; r < RP; ++r) {
    long row = row0 + (long)r * RG;
    if (row >= nrows) continue;
    float4 o = make_float4(acc[r][0], acc[r][1], acc[r][2], acc[r][3]);
    if (BIAS) {
      float4 bb = ((const float4*)sB)[cg];
      o.x += bb.x; o.y += bb.y; o.z += bb.z; o.w += bb.w;
    }
    if (ACT == 1) {
      o.x = fmaxf(o.x, 0.f); o.y = fmaxf(o.y, 0.f);
      o.z = fmaxf(o.z, 0.f); o.w = fmaxf(o.w, 0.f);
    }
    if (OBF16) {
      uint2 pk;
      pk.x = pack_bf2(o.x, o.y);
      pk.y = pack_bf2(o.z, o.w);
      ((uint2*)((__hip_bfloat16*)Cout + row * M))[cg] = pk;
    } else {
      ((float4*)((float*)Cout + row * M))[cg] = o;
    }
  }
}

// Pull aggregation, D=64 bf16: 16 lanes/node (4 feats = uint2 per lane),
// 4 nodes/wave, unroll 8. CSR lists are ~src-ascending (passive coherent
// sweep across co-resident waves). Output packed bf16 (uint2/lane).
__global__ __launch_bounds__(256) void k_agg64p(const uint2* __restrict__ hw,
                                                const int* __restrict__ csr,
                                                const int* __restrict__ rs,
                                                const int* __restrict__ cnt,
                                                const float* __restrict__ dis,
                                                const float* __restrict__ b,
                                                uint2* __restrict__ out, int n) {
  unsigned node = blockIdx.x * 16u + (threadIdx.x >> 4);
  if (node >= (unsigned)n) return;
  unsigned f4 = threadIdx.x & 15;
  float dsn = dis[node];
  uint2 su = hw[node * 16u + f4];
  float d2 = dsn * dsn;
  float a0 = bf_lo(su.x) * d2, a1 = bf_hi(su.x) * d2;
  float a2 = bf_lo(su.y) * d2, a3 = bf_hi(su.y) * d2;
  int start = rs[node], deg = cnt[node];
  int e = 0;
  for (; e + 7 < deg; e += 8) {
    unsigned s0 = (unsigned)csr[start + e];
    unsigned s1 = (unsigned)csr[start + e + 1];
    unsigned s2 = (unsigned)csr[start + e + 2];
    unsigned s3 = (unsigned)csr[start + e + 3];
    unsigned s4 = (unsigned)csr[start + e + 4];
    unsigned s5 = (unsigned)csr[start + e + 5];
    unsigned s6 = (unsigned)csr[start + e + 6];
    unsigned s7 = (unsigned)csr[start + e + 7];
    float w0 = dis[s0] * dsn, w1 = dis[s1] * dsn;
    float w2 = dis[s2] * dsn, w3 = dis[s3] * dsn;
    float w4 = dis[s4] * dsn, w5 = dis[s5] * dsn;
    float w6 = dis[s6] * dsn, w7 = dis[s7] * dsn;
    uint2 u0 = hw[s0 * 16u + f4];
    uint2 u1 = hw[s1 * 16u + f4];
    uint2 u2 = hw[s2 * 16u + f4];
    uint2 u3 = hw[s3 * 16u + f4];
    uint2 u4 = hw[s4 * 16u + f4];
    uint2 u5 = hw[s5 * 16u + f4];
    uint2 u6 = hw[s6 * 16u + f4];
    uint2 u7 = hw[s7 * 16u + f4];
    a0 += bf_lo(u0.x) * w0 + bf_lo(u1.x) * w1 + bf_lo(u2.x) * w2 + bf_lo(u3.x) * w3
        + bf_lo(u4.x) * w4 + bf_lo(u5.x) * w5 + bf_lo(u6.x) * w6 + bf_lo(u7.x) * w7;
    a1 += bf_hi(u0.x) * w0 + bf_hi(u1.x) * w1 + bf_hi(u2.x) * w2 + bf_hi(u3.x) * w3
        + bf_hi(u4.x) * w4 + bf_hi(u5.x) * w5 + bf_hi(u6.x) * w6 + bf_hi(u7.x) * w7;
    a2 += bf_lo(u0.y) * w0 + bf_lo(u1.y) * w1 + bf_lo(u2.y) * w2 + bf_lo(u3.y) * w3
        + bf_lo(u4.y) * w4 + bf_lo(u5.y) * w5 + bf_lo(u6.y) * w6 + bf_lo(u7.y) * w7;
    a3 += bf_hi(u0.y) * w0 + bf_hi(u1.y) * w1 + bf_hi(u2.y) * w2 + bf_hi(u3.y) * w3
        + bf_hi(u4.y) * w4 + bf_hi(u5.y) * w5 + bf_hi(u6.y) * w6 + bf_hi(u7.y) * w7;
  }
  for (; e < deg; ++e) {
    unsigned s0 = (unsigned)csr[start + e];
    float w0 = dis[s0] * dsn;
    uint2 u0 = hw[s0 * 16u + f4];
    a0 += bf_lo(u0.x) * w0;
    a1 += bf_hi(u0.x) * w0;
    a2 += bf_lo(u0.y) * w0;
    a3 += bf_hi(u0.y) * w0;
  }
  float4 bb = ((const float4*)b)[f4];
  uint2 pk;
  pk.x = pack_bf2(fmaxf(a0 + bb.x, 0.f), fmaxf(a1 + bb.y, 0.f));  // relu
  pk.y = pack_bf2(fmaxf(a2 + bb.z, 0.f), fmaxf(a3 + bb.w, 0.f));
  out[node * 16u + f4] = pk;
}

// Pull aggregation, D=32 bf16: 8 lanes/node (4 feats = uint2 per lane),
// 8 nodes/wave, unroll 8. fp32 output (this IS the h output in d_out).
__global__ __launch_bounds__(256) void k_agg32p(const uint2* __restrict__ hw,
                                                const int* __restrict__ csr,
                                                const int* __restrict__ rs,
                                                const int* __restrict__ cnt,
                                                const float* __restrict__ dis,
                                                const float* __restrict__ b,
                                                float* __restrict__ out, int n) {
  unsigned node = blockIdx.x * 32u + (threadIdx.x >> 3);
  if (node >= (unsigned)n) return;
  unsigned f4 = threadIdx.x & 7;
  float dsn = dis[node];
  uint2 su = hw[node * 8u + f4];
  float d2 = dsn * dsn;
  float a0 = bf_lo(su.x) * d2, a1 = bf_hi(su.x) * d2;
  float a2 = bf_lo(su.y) * d2, a3 = bf_hi(su.y) * d2;
  int start = rs[node], deg = cnt[node];
  int e = 0;
  for (; e + 7 < deg; e += 8) {
    unsigned s0 = (unsigned)csr[start + e];
    unsigned s1 = (unsigned)csr[start + e + 1];
    unsigned s2 = (unsigned)csr[start + e + 2];
    unsigned s3 = (unsigned)csr[start + e + 3];
    unsigned s4 = (unsigned)csr[start + e + 4];
    unsigned s5 = (unsigned)csr[start + e + 5];
    unsigned s6 = (unsigned)csr[start + e + 6];
    unsigned s7 = (unsigned)csr[start + e + 7];
    float w0 = dis[s0] * dsn, w1 = dis[s1] * dsn;
    float w2 = dis[s2] * dsn, w3 = dis[s3] * dsn;
    float w4 = dis[s4] * dsn, w5 = dis[s5] * dsn;
    float w6 = dis[s6] * dsn, w7 = dis[s7] * dsn;
    uint2 u0 = hw[s0 * 8u + f4];
    uint2 u1 = hw[s1 * 8u + f4];
    uint2 u2 = hw[s2 * 8u + f4];
    uint2 u3 = hw[s3 * 8u + f4];
    uint2 u4 = hw[s4 * 8u + f4];
    uint2 u5 = hw[s5 * 8u + f4];
    uint2 u6 = hw[s6 * 8u + f4];
    uint2 u7 = hw[s7 * 8u + f4];
    a0 += bf_lo(u0.x) * w0 + bf_lo(u1.x) * w1 + bf_lo(u2.x) * w2 + bf_lo(u3.x) * w3
        + bf_lo(u4.x) * w4 + bf_lo(u5.x) * w5 + bf_lo(u6.x) * w6 + bf_lo(u7.x) * w7;
    a1 += bf_hi(u0.x) * w0 + bf_hi(u1.x) * w1 + bf_hi(u2.x) * w2 + bf_hi(u3.x) * w3
        + bf_hi(u4.x) * w4 + bf_hi(u5.x) * w5 + bf_hi(u6.x) * w6 + bf_hi(u7.x) * w7;
    a2 += bf_lo(u0.y) * w0 + bf_lo(u1.y) * w1 + bf_lo(u2.y) * w2 + bf_lo(u3.y) * w3
        + bf_lo(u4.y) * w4 + bf_lo(u5.y) * w5 + bf_lo(u6.y) * w6 + bf_lo(u7.y) * w7;
    a3 += bf_hi(u0.y) * w0 + bf_hi(u1.y) * w1 + bf_hi(u2.y) * w2 + bf_hi(u3.y) * w3
        + bf_hi(u4.y) * w4 + bf_hi(u5.y) * w5 + bf_hi(u6.y) * w6 + bf_hi(u7.y) * w7;
  }
  for (; e < deg; ++e) {
    unsigned s0 = (unsigned)csr[start + e];
    float w0 = dis[s0] * dsn;
    uint2 u0 = hw[s0 * 8u + f4];
    a0 += bf_lo(u0.x) * w0;
    a1 += bf_hi(u0.x) * w0;
    a2 += bf_lo(u0.y) * w0;
    a3 += bf_hi(u0.y) * w0;
  }
  float4 bb = ((const float4*)b)[f4];
  ((float4*)(out + node * 32u))[f4] =
      make_float4(a0 + bb.x, a1 + bb.y, a2 + bb.z, a3 + bb.w);
}

// score = sigmoid(s[N,32] @ sW2[32] + sb2); 8 nodes per 256-thread block.
__global__ void k_score(const float* __restrict__ s, const float* __restrict__ sW2,
                        const float* __restrict__ sb2, float* __restrict__ out, int n) {
  int node = blockIdx.x * 8 + (threadIdx.x >> 5);
  int k = threadIdx.x & 31;
  if (node >= n) return;
  float v = s[(long)node * 32 + k] * sW2[k];
  for (int off = 16; off > 0; off >>= 1) v += __shfl_down(v, off, 32);
  if (k == 0) out[node] = 1.0f / (1.0f + expf(-(v + sb2[0])));
}

extern "C" void kernel_launch(void* const* d_in, const int* in_sizes, int n_in,
                              void* d_out, int out_size, void* d_ws, size_t ws_size,
                              hipStream_t stream) {
  const float* x   = (const float*)d_in[0];
  const void*  ei  = d_in[1];
  const float* W1  = (const float*)d_in[2];
  const float* b1  = (const float*)d_in[3];
  const float* W2  = (const float*)d_in[4];
  const float* b2  = (const float*)d_in[5];
  const float* rW1 = (const float*)d_in[6];
  const float* rb1 = (const float*)d_in[7];
  const float* rW2 = (const float*)d_in[8];
  const float* rb2 = (const float*)d_in[9];
  const float* sW1 = (const float*)d_in[10];
  const float* sb1 = (const float*)d_in[11];
  const float* sW2 = (const float*)d_in[12];
  const float* sb2 = (const float*)d_in[13];

  const int N = in_sizes[0] / 128;
  const int E = in_sizes[1] / 2;

  // bucket geometry: SPB = 1<<shift nodes per bucket, B buckets (<=256)
  int shift = 9;
  while ((((long)N + (1L << shift) - 1) >> shift) > 256) ++shift;
  const int SB = 32 - shift;               // src bits in packed pair (N < 2^SB here)
  const int B = (int)(((long)N + (1L << shift) - 1) >> shift);
  const int C = 512;                       // edge chunks
  const int CS = (E + C - 1) / C;          // edges per chunk
  const int L = B * C;

  // workspace layout (256B aligned chunks)
  char* w = (char*)d_ws;
  auto alloc = [&](size_t bytes) {
    char* p = w;
    w += (bytes + 255) & ~(size_t)255;
    return p;
  };
  int*   meta   = (int*)alloc(64);
  int*   cnt    = (int*)alloc((size_t)N * 4);
  int*   rs     = (int*)alloc((size_t)N * 4);
  float* dis    = (float*)alloc((size_t)N * 4);
  int*   bsumsL = (int*)alloc(1024);
  int*   bscan  = (int*)alloc(((size_t)L + 1) * 4);
  int*   csr    = (int*)alloc((size_t)E * 4);
  // union buffer: pairs (E*4B packed) -> later tbuf bf16 [N,64] / sbuf fp32 [N,32]
  size_t uni = (size_t)E * 4 > (size_t)N * 128 ? (size_t)E * 4 : (size_t)N * 128;
  char*  u      = alloc(uni);
  unsigned* pairs = (unsigned*)u;
  __hip_bfloat16* tbuf = (__hip_bfloat16*)u;   // recon intermediate [N,64] bf16
  float* sbuf   = (float*)u;                   // scorer intermediate [N,32] fp32
  uint2* hw1 = (uint2*)alloc((size_t)N * 64 * 2);  // bf16 [N][64]
  uint2* h1  = (uint2*)alloc((size_t)N * 64 * 2);  // bf16 [N][64]
  uint2* hw2 = (uint2*)alloc((size_t)N * 32 * 2);  // bf16 [N][32]

  float* h_out = (float*)d_out;                 // [N,32]
  float* x_rec = h_out + (long)N * 32;          // [N,128]
  float* score = x_rec + (long)N * 128;         // [N,1]

  // ---- CSR build (atomic-free two-level counting sort, src-sorted lists) ----
  k_detect<<<1, 256, 0, stream>>>((const unsigned int*)ei, E < 4096 ? E : 4096, meta);
  k_binhist<<<C, 256, 0, stream>>>(ei, E, CS, B, shift, meta, bscan, C);
  int nbL = (L + 1023) / 1024;
  k_scan1<<<nbL, 1024, 0, stream>>>(bscan, bsumsL, L);
  k_scan2<<<1, 128, 0, stream>>>(bsumsL, nbL);
  k_scan3s<<<nbL, 1024, 0, stream>>>(bscan, bsumsL, bscan, L, 1);  // in-place + sentinel
  k_binscatter<<<C, 256, 0, stream>>>(ei, E, CS, B, shift, SB, meta, bscan, C, pairs);
  k_bucketbuild<<<B, 256, 0, stream>>>(pairs, bscan, C, shift, SB, N, cnt, dis, rs, csr);

  // ---- layer 1: hw1 = bf16(x @ W1) ; h1 = bf16(relu(agg + b1)) ----
  k_gemm<128, 64, false, 0, false, true><<<(N + 63) / 64, 256, 0, stream>>>(x, W1, nullptr, hw1, N);
  k_agg64p<<<(N + 15) / 16, 256, 0, stream>>>(hw1, csr, rs, cnt, dis, b1, h1, N);

  // ---- layer 2: hw2 = bf16(h1 @ W2) ; h = agg + b2 -> d_out ----
  k_gemm<64, 32, false, 0, true, true><<<(N + 127) / 128, 256, 0, stream>>>(h1, W2, nullptr, hw2, N);
  k_agg32p<<<(N + 31) / 32, 256, 0, stream>>>(hw2, csr, rs, cnt, dis, b2, h_out, N);

  // ---- reconstruction MLP: t = bf16(relu(h@rW1+rb1)) ; x_rec = t@rW2+rb2 ----
  k_gemm<32, 64, true, 1, false, true><<<(N + 63) / 64, 256, 0, stream>>>(h_out, rW1, rb1, tbuf, N);
  k_gemm<64, 128, true, 0, true, false><<<(N + 31) / 32, 256, 0, stream>>>(tbuf, rW2, rb2, x_rec, N);

  // ---- scorer MLP: s = relu(h@sW1+sb1) ; score = sigmoid(s@sW2+sb2) ----
  k_gemm<32, 32, true, 1, false, false><<<(N + 127) / 128, 256, 0, stream>>>(h_out, sW1, sb1, sbuf, N);
  k_score<<<(N + 7) / 8, 256, 0, stream>>>(sbuf, sW2, sb2, score, N);
}